// Round 11
// baseline (191.001 us; speedup 1.0000x reference)
//
#include <hip/hip_runtime.h>
#include <stdint.h>

// Binarized ConvNet via XOR+popcount on packed bits.
// BN stats = exact integer sums (sharded global atomics); BN+sign folded into
// exact per-channel integer thresholds, computed redundantly per consumer wave.
// kA conv1 (direct register->global stores, plane-major conflict-free stats
// staging) + parallel weight-packer blocks; kB conv2 (R5-proven form);
// kC fc (4 images/wave); kD BN3-apply.

#define NB 8192
typedef unsigned long long ull;

// ---- ws layout ----
#define OFF_C1  ((size_t)0)                    // int8 [NB][196pos][32ch]
#define SZ_C1   ((size_t)NB*6272)
#define OFF_C2  (OFF_C1 + SZ_C1)               // int8 [NB][64ch][64pos] (o/2)
#define SZ_C2   ((size_t)NB*4096)
#define OFF_FC  (OFF_C2 + SZ_C2)               // int32 [NB][10]
#define SZ_FC   ((size_t)NB*10*4)
#define OFF_S1  (OFF_FC + SZ_FC)               // int  [8][32][2]   2048 B
#define OFF_S2  (OFF_S1 + 2048)                // ull  [8][64][2]   8192 B
#define OFF_S3  (OFF_S2 + 8192)                // ull  [8][10][2]   (pad 2048)
#define OFF_W2B (OFF_S3 + 2048)                // ull w2bT[8][64] (word-idx major)
#define OFF_W3B (OFF_W2B + 4096)               // ull w3b[10][64ch], bit=pos

// exact integer threshold: bit = (v >= T) ^ flip  <=>  s*v + t > 0
__device__ inline void mk_thresh(double s, double t, int &T, int &flip) {
    if (s > 0.0) {
        int v = (int)floor(-t / s) - 2;
        for (int c = 0; c < 6; ++c) { if (s * (double)v + t > 0.0) break; ++v; }
        T = v; flip = 0;
    } else if (s < 0.0) {
        int v = (int)floor(-t / s) - 2;
        for (int c = 0; c < 6; ++c) { if (!(s * (double)v + t > 0.0)) break; ++v; }
        T = v; flip = 1;
    } else { T = -200; flip = (t > 0.0) ? 0 : 1; }
}
__device__ inline int clampT(int T, int lim) {
    return (T < -lim) ? -lim : (T > lim) ? lim : T;
}

// ------------------------------------------------------------------
// KA: conv1 (binary) + integer BN1 stats.  1 wave = 1 image, 4/block.
// Direct register->global c1 stores; stats staged plane-major in LDS
// (conflict-free), per-plane shfl reduction (fixed channel binding).
// Blocks >= 2048: parallel weight packer (one thread per packed word).
// ------------------------------------------------------------------
__global__ __launch_bounds__(256) void kA_conv1(
    const float* __restrict__ x, const float* __restrict__ w1,
    const float* __restrict__ w2, const float* __restrict__ w3,
    int8_t* __restrict__ c1out, int* __restrict__ stats1,
    ull* __restrict__ w2bT, ull* __restrict__ w3b)
{
    const int tid = threadIdx.x, lane = tid & 63, wv = tid >> 6;

    if (blockIdx.x >= 2048) {   // ---- parallel weight packer blocks ----
        const int t = (blockIdx.x - 2048)*256 + tid;
        if (t < 512) {
            const int idx = t >> 6, k = t & 63;
            const int u = idx >> 1, pr = idx & 1;
            uint32_t lo = 0u, hi = 0u;
            #pragma unroll 8
            for (int c = 0; c < 32; ++c) {
                const float* wp = w2 + (((k*32 + c)*4 + u)*4 + 2*pr);
                lo |= (wp[0] > 0.f ? 1u : 0u) << c;
                hi |= (wp[1] > 0.f ? 1u : 0u) << c;
            }
            w2bT[t] = (ull)lo | ((ull)hi << 32);
        } else if (t < 1152) {
            const int w = t - 512;                 // w = m*64 + ch
            const float* wp = w3 + (size_t)(w >> 6)*4096 + (size_t)(w & 63)*64;
            ull bits = 0ull;
            #pragma unroll 16
            for (int k = 0; k < 64; ++k)
                bits |= (ull)(wp[k] > 0.f ? 1 : 0) << k;
            w3b[w] = bits;
        }
        return;
    }

    __shared__ ull sxb[4][16];              // 784 input sign bits, per wave
    __shared__ uint32_t wfilt[32];          // 25-bit filters
    __shared__ uint32_t obT[4][8][196];     // plane-major staging [wv][d][pos]
    __shared__ int lpart[4][8][4][2];       // per-wave reduced stats partials

    if (tid < 32) {
        uint32_t f = 0u;
        #pragma unroll
        for (int q = 0; q < 25; ++q) f |= (w1[tid*25 + q] > 0.f ? 1u : 0u) << q;
        wfilt[tid] = f;
    }
    __syncthreads();          // barrier 1: wfilt visible
    const int n = blockIdx.x*4 + wv;
    // phase A: pack 784 input sign bits (13 ballot rounds) — wave-local
    #pragma unroll
    for (int t = 0; t < 13; ++t) {
        const int idx = t*64 + lane;
        const float v = (idx < 784) ? x[(size_t)n*784 + idx] : -1.f;
        const ull bal = __ballot(v > 0.f);
        if (lane == t) sxb[wv][t] = bal;
    }
    if (lane == 13) sxb[wv][13] = 0ull;
    // phase B: each lane computes up to 4 positions, 32 channels each;
    // writes global DIRECTLY from registers + plane-major LDS for stats
    for (int t = 0; t < 4; ++t) {
        const int p = t*64 + lane;
        if (p < 196) {
            const int i = p / 14, j = p - i*14;
            const uint32_t cmask = (j == 0) ? 0x1Cu : (j == 13) ? 0x0Fu : 0x1Fu;
            uint32_t win = 0u, vm = 0u;
            #pragma unroll
            for (int u = 0; u < 5; ++u) {
                const int r = 2*i + u - 2;
                if (r >= 0 && r < 28) {
                    const int bp = 28*r, w0 = bp >> 6, sh = bp & 63;
                    const ull a = sxb[wv][w0], b = sxb[wv][w0+1];
                    uint32_t row = (uint32_t)((a >> sh) | ((b << 1) << (63 - sh)));
                    row = (row & 0x0FFFFFFFu) << 2;
                    win |= ((row >> (2*j)) & 31u) << (5*u);
                    vm  |= cmask << (5*u);
                }
            }
            const int nv = __popc(vm);
            uint32_t dw[8];
            #pragma unroll
            for (int d = 0; d < 8; ++d) dw[d] = 0u;
            #pragma unroll
            for (int c = 0; c < 32; ++c) {
                const int diff = __popc((win ^ wfilt[c]) & vm);
                const int o = nv - 2*diff;
                dw[c >> 2] |= (uint32_t)(o & 255) << (8*(c & 3));
            }
            uint4* dst = (uint4*)(c1out + (size_t)n*6272 + (size_t)p*32);
            dst[0] = make_uint4(dw[0], dw[1], dw[2], dw[3]);
            dst[1] = make_uint4(dw[4], dw[5], dw[6], dw[7]);
            #pragma unroll
            for (int d = 0; d < 8; ++d) obT[wv][d][p] = dw[d];
        }
    }
    // stats: per plane d (fixed channel binding d*4+qq), conflict-free reads
    #pragma unroll
    for (int d = 0; d < 8; ++d) {
        int s4[4] = {0,0,0,0}, q4[4] = {0,0,0,0};
        #pragma unroll
        for (int t = 0; t < 4; ++t) {
            const int pp = t*64 + lane;
            if (pp < 196) {
                const uint32_t v32 = obT[wv][d][pp];
                #pragma unroll
                for (int qq = 0; qq < 4; ++qq) {
                    const int v = (int)((int8_t)(v32 >> (8*qq)));
                    s4[qq] += v; q4[qq] += v*v;
                }
            }
        }
        #pragma unroll
        for (int off = 1; off <= 32; off <<= 1) {
            #pragma unroll
            for (int qq = 0; qq < 4; ++qq) {
                s4[qq] += __shfl_xor(s4[qq], off);
                q4[qq] += __shfl_xor(q4[qq], off);
            }
        }
        if (lane == 0) {
            #pragma unroll
            for (int qq = 0; qq < 4; ++qq) {
                lpart[wv][d][qq][0] = s4[qq];
                lpart[wv][d][qq][1] = q4[qq];
            }
        }
    }
    __syncthreads();          // barrier 2: all waves' partials in lpart
    if (tid < 32) {           // tid = channel = d*4+qq
        const int d = tid >> 2, qq = tid & 3;
        int s = 0, q = 0;
        #pragma unroll
        for (int w = 0; w < 4; ++w) {
            s += lpart[w][d][qq][0];
            q += lpart[w][d][qq][1];
        }
        const int shard = blockIdx.x & 7;
        atomicAdd(&stats1[(shard*32 + tid)*2 + 0], s);
        atomicAdd(&stats1[(shard*32 + tid)*2 + 1], q);
    }
}

// ------------------------------------------------------------------
// KB: per-wave BN1 thresholds, binarize c1, conv2 xor+popc (lane=ch,
// fully unrolled), register BN2 stats, int8 o/2 out [n][ch][pos].
// 1 wave = 1 image; W from global; cw padded 17.  (R5 best form)
// ------------------------------------------------------------------
__global__ __launch_bounds__(256) void kB_conv2(
    const int8_t* __restrict__ c1out, const int* __restrict__ stats1,
    const float* __restrict__ gm1, const float* __restrict__ bt1,
    const ull* __restrict__ w2bT,
    int8_t* __restrict__ c2out, ull* __restrict__ stats2)
{
    __shared__ ull BwU[4][14][8];       // packed input bits, per wave
    __shared__ int sT1[4][32];          // per-wave thresholds
    __shared__ uint32_t cw[4][64][17];  // staged out dwords, pad 17
    __shared__ int ssum[64], ssq[64];
    const int tid = threadIdx.x, lane = tid & 63, wv = tid >> 6;
    const int n = blockIdx.x*4 + wv;

    // W fragments straight from global (coalesced, L2-hot)
    ull W[8];
    #pragma unroll
    for (int idx = 0; idx < 8; ++idx) W[idx] = w2bT[idx*64 + lane];

    if (tid < 64) { ssum[tid] = 0; ssq[tid] = 0; }
    // per-wave redundant BN1 threshold computation (lanes 0-31)
    int fl = 0;
    if (lane < 32) {
        long long s = 0, q = 0;
        for (int sh = 0; sh < 8; ++sh) {
            s += stats1[(sh*32 + lane)*2 + 0];
            q += stats1[(sh*32 + lane)*2 + 1];
        }
        const double N = 8192.0 * 196.0;
        const double mean = (double)s / N;
        const double var  = (double)q / N - mean*mean;
        const double a = (double)gm1[lane] / sqrt(var + 1e-5);
        const double b = (double)bt1[lane] - mean*a;
        int T; mk_thresh(a, b, T, fl);
        sT1[wv][lane] = clampT(T, 26);
    }
    const uint32_t flipn1 = ~(uint32_t)__ballot(fl != 0);
    __syncthreads();          // barrier 1: ssum zeros (thresholds wave-local)

    // pack phase — wave-local: binarize own image's 196 positions
    for (int t = lane; t < 196; t += 64) {
        const int r = t / 14, c = t - r*14;
        const uint4* src = (const uint4*)(c1out + ((size_t)n*196 + t)*32);
        const uint4 lo4 = src[0], hi4 = src[1];
        const uint32_t wsrc[8] = {lo4.x, lo4.y, lo4.z, lo4.w, hi4.x, hi4.y, hi4.z, hi4.w};
        uint32_t neg = 0u;
        #pragma unroll
        for (int d = 0; d < 8; ++d) {
            #pragma unroll
            for (int qq = 0; qq < 4; ++qq) {
                const int ch = d*4 + qq;
                const int v = (int)((int8_t)(wsrc[d] >> (8*qq)));
                neg |= ((uint32_t)(v - sT1[wv][ch]) >> 31) << ch;   // 1 iff v<T
            }
        }
        ((uint32_t*)&BwU[wv][r][0])[c] = neg ^ flipn1;
    }
    // compute phase — wave-local: lane = out-channel, unrolled 64 positions
    int s = 0, q = 0;
    #pragma unroll
    for (int i = 0; i < 8; ++i) {
        uint32_t packA = 0u;
        #pragma unroll
        for (int j = 0; j < 8; ++j) {
            int D = 0, nw = 0;
            #pragma unroll
            for (int u = 0; u < 4; ++u) {
                const int r = 2*i + u - 2;
                if (r < 0 || r > 13) continue;           // compile-time
                const ull* row = &BwU[wv][r][0];
                if (j >= 1) { D += __popcll(row[j-1] ^ W[2*u+0]); ++nw; }
                if (j <= 6) { D += __popcll(row[j]   ^ W[2*u+1]); ++nw; }
            }
            const int o = 32*nw - D;                     // = full/2, exact
            s += o; q += o*o;
            packA |= (uint32_t)(o & 255) << (8*(j & 3));
            if ((j & 3) == 3) { cw[wv][lane][2*i + (j >> 2)] = packA; packA = 0u; }
        }
    }
    atomicAdd(&ssum[lane], s);
    atomicAdd(&ssq[lane], q);
    {   // coalesced writeout [n][ch][pos] — wave-local, dword-wise
        uint32_t* dst = (uint32_t*)(c2out + (size_t)n*4096);
        #pragma unroll
        for (int t = 0; t < 16; ++t) {
            const int g = t*64 + lane;
            dst[g] = cw[wv][g >> 4][g & 15];
        }
    }
    __syncthreads();          // barrier 2: all waves' stats in ssum/ssq
    if (tid < 64) {
        const int shard = blockIdx.x & 7;
        atomicAdd(&stats2[(shard*64 + tid)*2 + 0], (ull)(long long)ssum[tid]);
        atomicAdd(&stats2[(shard*64 + tid)*2 + 1], (ull)(long long)ssq[tid]);
    }
}

// ------------------------------------------------------------------
// KC: per-lane BN2 thresholds (lane=ch), binarize arithmetically,
// fc xor+popc, packed shuffle reduction, BN3 stats.
// 1 wave = 4 images (thresholds amortized), 16 images/block.
// ------------------------------------------------------------------
__global__ __launch_bounds__(256) void kC_fc(
    const int8_t* __restrict__ c2o, const float* __restrict__ gm2,
    const float* __restrict__ bt2, const ull* __restrict__ stats2,
    const ull* __restrict__ w3b,
    int* __restrict__ fc, ull* __restrict__ stats3)
{
    __shared__ int fco[16][10];
    __shared__ int s3[10], q3[10];
    const int tid = threadIdx.x, lane = tid & 63, wv = tid >> 6;
    if (tid < 10) { s3[tid] = 0; q3[tid] = 0; }
    // per-lane BN2 threshold for own channel (values stored are o/2)
    int T2, fl;
    {
        long long ss = 0, qq = 0;
        for (int sh = 0; sh < 8; ++sh) {
            ss += (long long)stats2[(sh*64 + lane)*2 + 0];
            qq += (long long)stats2[(sh*64 + lane)*2 + 1];
        }
        const double N = 8192.0 * 64.0;
        const double mh = (double)ss / N;
        const double vh = (double)qq / N - mh*mh;
        const double a = (double)gm2[lane] / sqrt(4.0*vh + 1e-5);
        const double b = (double)bt2[lane] - 2.0*mh*a;
        int T; mk_thresh(2.0*a, b, T, fl);
        T2 = clampT(T, 200);
    }
    const ull flipn2 = ~__ballot(fl != 0);
    const int n0 = blockIdx.x*16 + wv*4;
    // build 4 images' bit-words
    ull myw[4];
    #pragma unroll
    for (int im = 0; im < 4; ++im) {
        const uint4* src = (const uint4*)(c2o + (size_t)(n0+im)*4096 + lane*64);
        uint32_t neglo = 0u, neghi = 0u;
        #pragma unroll
        for (int r4 = 0; r4 < 4; ++r4) {
            const uint4 v4 = src[r4];
            const uint32_t wsrc[4] = {v4.x, v4.y, v4.z, v4.w};
            #pragma unroll
            for (int cc = 0; cc < 4; ++cc) {
                #pragma unroll
                for (int b = 0; b < 4; ++b) {
                    const int p = r4*16 + cc*4 + b;
                    const int v = (int)((int8_t)(wsrc[cc] >> (8*b)));
                    const uint32_t bit = (uint32_t)(v - T2) >> 31;   // 1 iff v<T
                    if (p < 32) neglo |= bit << p; else neghi |= bit << (p - 32);
                }
            }
        }
        myw[im] = ((ull)neglo | ((ull)neghi << 32)) ^ flipn2;
    }
    // 10 outputs x 4 images: w3 words loaded once per pair, reused
    uint32_t pk[4][5];
    #pragma unroll
    for (int t = 0; t < 5; ++t) {
        const ull wA = w3b[(2*t+0)*64 + lane];
        const ull wB = w3b[(2*t+1)*64 + lane];
        #pragma unroll
        for (int im = 0; im < 4; ++im) {
            const uint32_t pa = (uint32_t)__popcll(myw[im] ^ wA);
            const uint32_t pb = (uint32_t)__popcll(myw[im] ^ wB);
            pk[im][t] = pa | (pb << 16);
        }
    }
    #pragma unroll
    for (int off = 32; off >= 1; off >>= 1) {
        #pragma unroll
        for (int im = 0; im < 4; ++im)
            #pragma unroll
            for (int t = 0; t < 5; ++t) pk[im][t] += __shfl_xor(pk[im][t], off);
    }
    if (lane == 0) {
        #pragma unroll
        for (int im = 0; im < 4; ++im)
            #pragma unroll
            for (int m = 0; m < 10; ++m) {
                const int tot = (pk[im][m >> 1] >> (16*(m & 1))) & 0xFFFF;
                fco[wv*4 + im][m] = 4096 - 2*tot;
            }
    }
    __syncthreads();
    if (tid < 160) {
        const int li = tid / 10, m = tid - li*10;
        const int o = fco[li][m];
        fc[(size_t)(blockIdx.x*16 + li)*10 + m] = o;
        atomicAdd(&s3[m], o);
        atomicAdd(&q3[m], o*o);
    }
    __syncthreads();
    if (tid < 10) {
        const int shard = blockIdx.x & 7;
        atomicAdd(&stats3[(shard*10 + tid)*2 + 0], (ull)(long long)s3[tid]);
        atomicAdd(&stats3[(shard*10 + tid)*2 + 1], (ull)(long long)q3[tid]);
    }
}

// ------------------------------------------------------------------
// KD: reduce BN3 stats (per block, redundant) + apply -> d_out (fp32)
// ------------------------------------------------------------------
__global__ __launch_bounds__(256) void kD_apply(
    const int* __restrict__ fc, const float* __restrict__ gm3,
    const float* __restrict__ bt3, const ull* __restrict__ stats3,
    float* __restrict__ out)
{
    __shared__ float a3[10], b3[10];
    const int tid = threadIdx.x;
    if (tid < 10) {
        long long s = 0, q = 0;
        for (int sh = 0; sh < 8; ++sh) {
            s += (long long)stats3[(sh*10 + tid)*2 + 0];
            q += (long long)stats3[(sh*10 + tid)*2 + 1];
        }
        const double N = 8192.0;
        const double mean = (double)s / N;
        const double var  = (double)q / N - mean*mean;
        const double a = (double)gm3[tid] / sqrt(var + 1e-5);
        a3[tid] = (float)a;
        b3[tid] = (float)((double)bt3[tid] - mean*a);
    }
    __syncthreads();
    const int e = blockIdx.x*256 + tid;
    if (e < NB*10) {
        const int m = e % 10;
        out[e] = fmaf(a3[m], (float)fc[e], b3[m]);
    }
}

extern "C" void kernel_launch(void* const* d_in, const int* in_sizes, int n_in,
                              void* d_out, int out_size, void* d_ws, size_t ws_size,
                              hipStream_t stream)
{
    const float* x   = (const float*)d_in[0];
    const float* w1  = (const float*)d_in[1];
    const float* gm1 = (const float*)d_in[2];
    const float* bt1 = (const float*)d_in[3];
    const float* w2  = (const float*)d_in[4];
    const float* gm2 = (const float*)d_in[5];
    const float* bt2 = (const float*)d_in[6];
    const float* w3  = (const float*)d_in[7];
    const float* gm3 = (const float*)d_in[8];
    const float* bt3 = (const float*)d_in[9];
    char* ws = (char*)d_ws;
    int8_t* c1o = (int8_t*)(ws + OFF_C1);
    int8_t* c2o = (int8_t*)(ws + OFF_C2);
    int*    fcb = (int*)(ws + OFF_FC);
    int*    s1  = (int*)(ws + OFF_S1);
    ull*    s2  = (ull*)(ws + OFF_S2);
    ull*    s3  = (ull*)(ws + OFF_S3);
    ull*    w2bp = (ull*)(ws + OFF_W2B);
    ull*    w3bp = (ull*)(ws + OFF_W3B);

    (void)hipMemsetAsync(ws + OFF_S1, 0, 12288, stream);
    kA_conv1<<<2053, 256, 0, stream>>>(x, w1, w2, w3, c1o, s1, w2bp, w3bp);
    kB_conv2<<<2048, 256, 0, stream>>>(c1o, s1, gm1, bt1, w2bp, c2o, s2);
    kC_fc   <<<512,  256, 0, stream>>>(c2o, gm2, bt2, s2, w3bp, fcb, s3);
    kD_apply<<<320,  256, 0, stream>>>(fcb, gm3, bt3, s3, (float*)d_out);
}